// Round 6
// baseline (123.207 us; speedup 1.0000x reference)
//
#include <hip/hip_runtime.h>
#include <hip/hip_bf16.h>
#include <math.h>

#define BATCH 16
#define LEN   160000
#define NFFT  512
#define HOP   128
#define NT    1251      // 1 + (160000+512-512)/128
#define NF    257
#define PADC  256
#define TWO_PI 6.28318530717958647692f
// padded LDS index: +1 float per 32 -> breaks power-of-2 bank aliasing
#define P(i) ((i) + ((i) >> 5))
#define FBUF 528        // padded 512-float FFT region (P(511)=526 < 528)
#define GSTR 264        // staging row stride: 2 rows == FBUF exactly

typedef unsigned int u32;
typedef unsigned short u16t;

__device__ __forceinline__ float rcpf(float x)  { return __builtin_amdgcn_rcpf(x); }
__device__ __forceinline__ float sqrtf_fast(float x) { return __builtin_amdgcn_sqrtf(x); }

__device__ __forceinline__ int reflect_idx(int j) {
    j = j < 0 ? -j : j;
    j = j >= LEN ? 2*LEN - 2 - j : j;
    return j;
}

__device__ __forceinline__ float hann(int n) {
    return 0.5f - 0.5f * __cosf(TWO_PI * (float)n * (1.0f / 512.0f));
}

// hann(j + 64r) for r=0..7 from ONE sincos: cos(th + r*pi/4) expanded over
// compile-time constants. Replaces 8 v_cos with 1 sincos + ~10 FMA.
__device__ __forceinline__ void hann8(int j, float wdv[8]) {
    float sth, cth;
    __sincosf((TWO_PI / 512.0f) * (float)j, &sth, &cth);
    const float K8 = 0.70710678118654752f;
    const float A = 0.5f * K8 * (cth - sth);
    const float B = 0.5f * K8 * (cth + sth);
    wdv[0] = 0.5f - 0.5f * cth;
    wdv[1] = 0.5f - A;
    wdv[2] = 0.5f + 0.5f * sth;
    wdv[3] = 0.5f + B;
    wdv[4] = 0.5f + 0.5f * cth;
    wdv[5] = 0.5f + A;
    wdv[6] = 0.5f - 0.5f * sth;
    wdv[7] = 0.5f - B;
}

__device__ __forceinline__ __hip_bfloat162 pack_bf2(float x, float y) {
    __hip_bfloat162 r; r.x = __float2bfloat16(x); r.y = __float2bfloat16(y); return r;
}
__device__ __forceinline__ float2 unpack_bf2(__hip_bfloat162 v) {
    return make_float2(__bfloat162float(v.x), __bfloat162float(v.y));
}

// ---------- scalar sorted-4-smallest (used only for the f=256 column) ----------
struct T4 { float m0, m1, m2, m3; };   // ascending

__device__ __forceinline__ void ins(T4& a, float v) {
    const float x0 = fminf(a.m0, v);  const float c0 = fmaxf(a.m0, v);
    const float x1 = fminf(a.m1, c0); const float c1 = fmaxf(a.m1, c0);
    const float x2 = fminf(a.m2, c1); const float c2 = fmaxf(a.m2, c1);
    const float x3 = fminf(a.m3, c2);
    a.m0 = x0; a.m1 = x1; a.m2 = x2; a.m3 = x3;
}

// ---------- PACKED u16 sorted-4-smallest via FORCED v_pk_min/max_u16 ----------
// n_mag is strictly positive bf16 -> u16 bit order == value order. Two
// independent 16-bit lanes per u32 (groups A/B of the two-stacks quantile).
__device__ __forceinline__ u32 pminP(u32 a, u32 b) {
    u32 d; asm("v_pk_min_u16 %0, %1, %2" : "=v"(d) : "v"(a), "v"(b)); return d;
}
__device__ __forceinline__ u32 pmaxP(u32 a, u32 b) {
    u32 d; asm("v_pk_max_u16 %0, %1, %2" : "=v"(d) : "v"(a), "v"(b)); return d;
}

struct PT4 { u32 m0, m1, m2, m3; };   // ascending per 16-bit lane

__device__ __forceinline__ void insP(PT4& a, u32 v) {
    const u32 x0 = pminP(a.m0, v);  const u32 c0 = pmaxP(a.m0, v);
    const u32 x1 = pminP(a.m1, c0); const u32 c1 = pmaxP(a.m1, c0);
    const u32 x2 = pminP(a.m2, c1); const u32 c2 = pmaxP(a.m2, c1);
    const u32 x3 = pminP(a.m3, c2);
    a.m0 = x0; a.m1 = x1; a.m2 = x2; a.m3 = x3;
}

__device__ __forceinline__ PT4 sort4P(u32 a, u32 b, u32 c, u32 d) {
    const u32 x0 = pminP(a, b), x1 = pmaxP(a, b);
    const u32 x2 = pminP(c, d), x3 = pmaxP(c, d);
    const u32 y0 = pminP(x0, x2), y2 = pmaxP(x0, x2);
    const u32 y1 = pminP(x1, x3), y3 = pmaxP(x1, x3);
    PT4 r; r.m0 = y0; r.m1 = pminP(y1, y2); r.m2 = pmaxP(y1, y2); r.m3 = y3;
    return r;
}

// full sorted merge: 4-smallest of union(a,b), ascending. 12 ops.
__device__ __forceinline__ PT4 merge4P(const PT4& a, const PT4& b) {
    const u32 l0 = pminP(a.m0, b.m3);
    const u32 l1 = pminP(a.m1, b.m2);
    const u32 l2 = pminP(a.m2, b.m1);
    const u32 l3 = pminP(a.m3, b.m0);
    const u32 t0 = pminP(l0, l2), t2 = pmaxP(l0, l2);
    const u32 t1 = pminP(l1, l3), t3 = pmaxP(l1, l3);
    PT4 r;
    r.m0 = pminP(t0, t1); r.m1 = pmaxP(t0, t1);
    r.m2 = pminP(t2, t3); r.m3 = pmaxP(t2, t3);
    return r;
}

__device__ __forceinline__ u32 merge4_m3P(const PT4& a, const PT4& b) {
    const u32 l0 = pminP(a.m0, b.m3);
    const u32 l1 = pminP(a.m1, b.m2);
    const u32 l2 = pminP(a.m2, b.m1);
    const u32 l3 = pminP(a.m3, b.m0);
    return pmaxP(pmaxP(l0, l1), pmaxP(l2, l3));
}

// 8-point DFT in registers. y[m] = sum_r v[r] * exp(sign*2*pi*i*r*m/8).
__device__ __forceinline__ void dft8(float vr[8], float vi[8], float sign) {
    const float K = 0.70710678118654752f;
    float ar=vr[0]+vr[4], ai=vi[0]+vi[4];
    float br=vr[0]-vr[4], bi=vi[0]-vi[4];
    float cr=vr[2]+vr[6], ci=vi[2]+vi[6];
    float dr=vr[2]-vr[6], di=vi[2]-vi[6];
    float er=vr[1]+vr[5], ei=vi[1]+vi[5];
    float fr=vr[1]-vr[5], fi=vi[1]-vi[5];
    float gr=vr[3]+vr[7], gi=vi[3]+vi[7];
    float hr=vr[3]-vr[7], hi=vi[3]-vi[7];
    const float W4dr = -sign*di, W4di = sign*dr;
    const float W4hr = -sign*hi, W4hi = sign*hr;
    const float E0r=ar+cr, E0i=ai+ci, E2r=ar-cr, E2i=ai-ci;
    const float E1r=br+W4dr, E1i=bi+W4di, E3r=br-W4dr, E3i=bi-W4di;
    const float O0r=er+gr, O0i=ei+gi, O2r=er-gr, O2i=ei-gi;
    const float O1r=fr+W4hr, O1i=fi+W4hi, O3r=fr-W4hr, O3i=fi-W4hi;
    const float T1r = K*(O1r - sign*O1i), T1i = K*(O1i + sign*O1r);
    const float T2r = -sign*O2i,          T2i = sign*O2r;
    const float T3r = K*(-O3r - sign*O3i), T3i = K*(-O3i + sign*O3r);
    vr[0]=E0r+O0r; vi[0]=E0i+O0i;  vr[4]=E0r-O0r; vi[4]=E0i-O0i;
    vr[1]=E1r+T1r; vi[1]=E1i+T1i;  vr[5]=E1r-T1r; vi[5]=E1i-T1i;
    vr[2]=E2r+T2r; vi[2]=E2i+T2i;  vr[6]=E2r-T2r; vi[6]=E2i-T2i;
    vr[3]=E3r+T3r; vi[3]=E3i+T3i;  vr[7]=E3r-T3r; vi[7]=E3i-T3i;
}

// One Stockham radix-8 pass, IN PLACE, one wave = one FFT (j in 0..63).
// Barrier-free: all ds_reads precede all ds_writes in program order.
template<int NS>
__device__ __forceinline__ void fft_pass(float* R, float* I, int j, float sign) {
    float vr[8], vi[8];
    #pragma unroll
    for (int r = 0; r < 8; ++r) { vr[r] = R[P(j + 64*r)]; vi[r] = I[P(j + 64*r)]; }
    const float th = sign * (TWO_PI / (8.0f * (float)NS)) * (float)(j & (NS - 1));
    float w1r, w1i; __sincosf(th, &w1i, &w1r);
    float wr = w1r, wi = w1i;
    #pragma unroll
    for (int r = 1; r < 8; ++r) {
        const float tr = vr[r]*wr - vi[r]*wi;
        vi[r] = vr[r]*wi + vi[r]*wr; vr[r] = tr;
        const float nwr = wr*w1r - wi*w1i;
        wi = wr*w1i + wi*w1r; wr = nwr;
    }
    dft8(vr, vi, sign);
    const int base = ((j / NS) * (8 * NS)) + (j & (NS - 1));
    #pragma unroll
    for (int r = 0; r < 8; ++r) { R[P(base + r*NS)] = vr[r]; I[P(base + r*NS)] = vi[r]; }
}

// Final pass (NS=64): results stay in REGISTERS. After this, lane j holds
// y[j + 64r] in vr[r]/vi[r]. No LDS write.
__device__ __forceinline__ void fft_pass_last(const float* R, const float* I, int j,
                                              float sign, float vr[8], float vi[8]) {
    #pragma unroll
    for (int r = 0; r < 8; ++r) { vr[r] = R[P(j + 64*r)]; vi[r] = I[P(j + 64*r)]; }
    const float th = sign * (TWO_PI / 512.0f) * (float)j;
    float w1r, w1i; __sincosf(th, &w1i, &w1r);
    float wr = w1r, wi = w1i;
    #pragma unroll
    for (int r = 1; r < 8; ++r) {
        const float tr = vr[r]*wr - vi[r]*wi;
        vi[r] = vr[r]*wi + vi[r]*wr; vr[r] = tr;
        const float nwr = wr*w1r - wi*w1i;
        wi = wr*w1i + wi*w1r; wr = nwr;
    }
    dft8(vr, vi, sign);
}

// K1: STFT of BOTH signals via one complex FFT per frame: z = enh + i*noi.
// 4 frames per block (one per wave), wave-autonomous in-place radix-8
// Stockham, ZERO __syncthreads. Last pass in registers; Hermitian partner
// via __shfl. Outputs stored as BF16. Also zeroes the OLA output buffer.
__global__ __launch_bounds__(256, 6) void stft_kernel(const float* __restrict__ enh,
                                                      const float* __restrict__ noi,
                                                      __hip_bfloat162* __restrict__ e_spec,
                                                      __hip_bfloat16*  __restrict__ n_mag,
                                                      float* __restrict__ out) {
    __shared__ float Ar[4*FBUF], Ai[4*FBUF];
    const int tid = threadIdx.x;
    const int w = tid >> 6, j = tid & 63;
    const int tr_ = blockIdx.x * 4 + w;
    const bool live = tr_ < NT;
    const int t = live ? tr_ : NT - 1;
    const int b = blockIdx.y;
    float* ar = Ar + w*FBUF; float* ai = Ai + w*FBUF;

    // zero the output slice (fire-and-forget stores; K3 waits on this kernel)
    {
        const int z = (blockIdx.x << 9) + (tid << 1);
        if (z < LEN) *reinterpret_cast<float2*>(out + (size_t)b * LEN + z) = make_float2(0.0f, 0.0f);
    }

    // pass 0: global -> registers (windowed), dft8, write A
    {
        const int sbase = t * HOP - PADC;
        float vr[8], vi[8];
        if (sbase >= 0 && sbase + NFFT <= LEN) {
            const float* __restrict__ pe = enh + b * LEN + sbase;
            const float* __restrict__ pn = noi + b * LEN + sbase;
            float wdv[8];
            hann8(j, wdv);
            #pragma unroll
            for (int r = 0; r < 8; ++r) {
                const int n = j + 64*r;
                vr[r] = pe[n] * wdv[r];
                vi[r] = pn[n] * wdv[r];
            }
        } else {
            const float* __restrict__ pe = enh + b * LEN;
            const float* __restrict__ pn = noi + b * LEN;
            #pragma unroll
            for (int r = 0; r < 8; ++r) {
                const int n = j + 64*r;
                const int idx = reflect_idx(sbase + n);
                const float wd = hann(n);
                vr[r] = pe[idx] * wd;
                vi[r] = pn[idx] * wd;
            }
        }
        dft8(vr, vi, -1.0f);
        #pragma unroll
        for (int r = 0; r < 8; ++r) { ar[P(8*j + r)] = vr[r]; ai[P(8*j + r)] = vi[r]; }
    }
    fft_pass<8>(ar, ai, j, -1.0f);
    float zr[8], zi[8];
    fft_pass_last(ar, ai, j, -1.0f, zr, zi);

    // Hermitian partner via cross-lane shuffle (regs 4..7 of lane (64-j)&63)
    const int src = (64 - j) & 63;
    float pr[4], pi_[4];
    #pragma unroll
    for (int q = 4; q < 8; ++q) {
        pr[q-4]  = __shfl(zr[q], src);
        pi_[q-4] = __shfl(zi[q], src);
    }
    if (live) {
        const int obase = (b * NT + t) * NF;
        #pragma unroll
        for (int r = 0; r < 4; ++r) {
            const int kk = j + 64*r;
            const float yr = (j == 0) ? zr[(8 - r) & 7] : pr[3 - r];
            const float yi = (j == 0) ? zi[(8 - r) & 7] : pi_[3 - r];
            const float er = 0.5f*(zr[r] + yr), ei = 0.5f*(zi[r] - yi);
            const float nr = 0.5f*(zi[r] + yi), ni = 0.5f*(yr - zr[r]);
            e_spec[obase + kk] = pack_bf2(er, ei);
            n_mag[obase + kk] = __float2bfloat16(fmaxf(sqrtf_fast(nr*nr + ni*ni), 1e-6f));
        }
        if (j == 0) {   // kk = 256: self-conjugate bin
            e_spec[obase + 256] = pack_bf2(zr[4], 0.0f);
            n_mag[obase + 256] = __float2bfloat16(fmaxf(fabsf(zi[4]), 1e-6f));
        }
    }
}

// Packed two-stacks quantile with SPLIT-PREFIX ILP: windows k=0..7 in lo16,
// k=8..15 in hi16. Suffix S[k] over W[k..8); prefix split into TWO independent
// chains: Pa = 4-smallest of W[8..23) (fixed), Pb = streaming over W[23..31+k).
// Per window: m3(merge(S[k], merge4(Pa,Pb))). Two ~15-long chains instead of
// one ~30-long -> half the serial latency. Bit-identical 4th-smallest.
template<bool CL>
__device__ __forceinline__ void phaseQP(const u16t* __restrict__ pbu,
                                        int t0, int f, float qv[16]) {
    u16t wlo[16];
    #pragma unroll
    for (int r = 0; r < 16; ++r) {
        int tr = t0 - 19 + r;
        if (CL) { tr = tr < 0 ? 0 : (tr > NT - 1 ? NT - 1 : tr); }
        wlo[r] = pbu[tr * NF + f];
    }
    PT4 S[8];
    S[7].m0 = (u32)wlo[7] | ((u32)wlo[15] << 16);
    S[7].m1 = S[7].m2 = S[7].m3 = 0xFFFFFFFFu;
    #pragma unroll
    for (int k = 6; k >= 0; --k) {
        S[k] = S[k+1];
        insP(S[k], (u32)wlo[k] | ((u32)wlo[k+8] << 16));
    }
    // ring[r&7] holds w_abs[r] (the lo element) for the prefix stream
    u16t ring[8];
    #pragma unroll
    for (int i = 0; i < 8; ++i) ring[i] = wlo[8 + i];

    // ---- chain Pa: W[8..23), 15 elements (independent of Pb) ----
    PT4 Pa;
    {
        u32 Wt[4];
        #pragma unroll
        for (int r = 8; r < 12; ++r) {
            int tr = t0 - 19 + r + 8;
            if (CL) { tr = tr < 0 ? 0 : (tr > NT - 1 ? NT - 1 : tr); }
            const u16t hi = pbu[tr * NF + f];
            Wt[r - 8] = (u32)ring[r & 7] | ((u32)hi << 16);
            ring[r & 7] = hi;
        }
        Pa = sort4P(Wt[0], Wt[1], Wt[2], Wt[3]);
    }
    #pragma unroll
    for (int r = 12; r < 23; ++r) {
        int tr = t0 - 19 + r + 8;
        if (CL) { tr = tr < 0 ? 0 : (tr > NT - 1 ? NT - 1 : tr); }
        const u16t hi = pbu[tr * NF + f];
        insP(Pa, (u32)ring[r & 7] | ((u32)hi << 16));
        ring[r & 7] = hi;
    }
    // ---- chain Pb: W[23..31) initial, then streams W[31..38) ----
    PT4 Pb;
    {
        u32 Wt[4];
        #pragma unroll
        for (int r = 23; r < 27; ++r) {
            int tr = t0 - 19 + r + 8;
            if (CL) { tr = tr < 0 ? 0 : (tr > NT - 1 ? NT - 1 : tr); }
            const u16t hi = pbu[tr * NF + f];
            Wt[r - 23] = (u32)ring[r & 7] | ((u32)hi << 16);
            ring[r & 7] = hi;
        }
        Pb = sort4P(Wt[0], Wt[1], Wt[2], Wt[3]);
    }
    #pragma unroll
    for (int r = 27; r < 31; ++r) {
        int tr = t0 - 19 + r + 8;
        if (CL) { tr = tr < 0 ? 0 : (tr > NT - 1 ? NT - 1 : tr); }
        const u16t hi = pbu[tr * NF + f];
        insP(Pb, (u32)ring[r & 7] | ((u32)hi << 16));
        ring[r & 7] = hi;
    }
    {
        const PT4 M = merge4P(Pa, Pb);
        const u32 m = merge4_m3P(S[0], M);
        qv[0] = __uint_as_float(m << 16);
        qv[8] = __uint_as_float(m & 0xFFFF0000u);
    }
    #pragma unroll
    for (int k = 1; k < 8; ++k) {
        const int r = 30 + k;
        int tr = t0 - 19 + r + 8;
        if (CL) { tr = tr < 0 ? 0 : (tr > NT - 1 ? NT - 1 : tr); }
        const u16t hi = pbu[tr * NF + f];
        insP(Pb, (u32)ring[r & 7] | ((u32)hi << 16));
        ring[r & 7] = hi;
        const PT4 M = merge4P(Pa, Pb);
        const u32 m = merge4_m3P(S[k], M);
        qv[k]     = __uint_as_float(m << 16);
        qv[8 + k] = __uint_as_float(m & 0xFFFF0000u);
    }
}

// K3 (FUSED): [rolling-quantile floor + pools + mask + ISTFT + OLA].
// Split-prefix packed quantile (2x ILP); TP buffer de-aliased from gr/gi
// staging (+8.4KB LDS) -> one fewer __syncthreads (3 total). OLA interior
// fast path. (256,4): cap 128 VGPR, no spill.
__global__ __launch_bounds__(256, 4) void floor_mask_istft_kernel(
        const __hip_bfloat162* __restrict__ g,
        const __hip_bfloat16* __restrict__ n_mag,
        float* __restrict__ out) {
    __shared__ float smem[24 * GSTR];   // TP[8][GSTR] | gr[8*GSTR] | gi[8*GSTR]
    float* TPl = smem;                  // time-pooled rows, 8 x GSTR
    float* gr = smem + 8 * GSTR;
    float* gi = smem + 16 * GSTR;

    const int tid = threadIdx.x;
    const int w = tid >> 6, j = tid & 63;
    const int t0 = blockIdx.x * 8, b = blockIdx.y;
    const __hip_bfloat16* __restrict__ pb = n_mag + b * NT * NF;
    const u16t* __restrict__ pbu = (const u16t*)pb;
    const int f = tid;

    // ---- phase Q: 16 quantile rows (tq = t0-4+k) for f = tid, packed ----
    float qv[16];
    if (t0 >= 19 && t0 + 26 <= NT - 1) {        // 151/157 blocks: no clamp
        phaseQP<false>(pbu, t0, f, qv);
    } else {
        phaseQP<true>(pbu, t0, f, qv);
        #pragma unroll
        for (int k = 0; k < 16; ++k) {          // zero-pad rows outside [0,NT)
            const int tq = t0 - 4 + k;
            if (tq < 0 || tq >= NT) qv[k] = 0.0f;
        }
    }
    // ---- time pool k=9 in registers -> TP rows in LDS ----
    {
        float acc = 0.0f;
        #pragma unroll
        for (int k = 0; k < 9; ++k) acc += qv[k];
        #pragma unroll
        for (int to = 0; to < 8; ++to) {
            TPl[to * GSTR + f] = acc * (1.0f / 9.0f);
            if (to < 7) acc += qv[to + 9] - qv[to];
        }
    }
    // f = 256 column: scalar quantile + shuffle time-pool (lanes 0..15, wave 0)
    if (tid < 16) {
        const int k = tid;
        T4 m; m.m0 = m.m1 = m.m2 = m.m3 = 3.4e38f;
        for (int dt = -15; dt <= 15; ++dt) {
            int tt = t0 - 4 + k + dt;
            tt = tt < 0 ? 0 : (tt > NT - 1 ? NT - 1 : tt);
            ins(m, __bfloat162float(pb[tt * NF + 256]));
        }
        float qk = m.m3;
        const int tq = t0 - 4 + k;
        if (tq < 0 || tq >= NT) qk = 0.0f;
        float acc = 0.0f;
        #pragma unroll
        for (int d = 0; d < 9; ++d) acc += __shfl(qk, k + d);   // valid for k<8
        if (tid < 8) TPl[tid * GSTR + 256] = acc * (1.0f / 9.0f);
    }
    __syncthreads();   // TP rows complete (cross-thread freq-pool reads follow)

    // ---- freq pool k=5 (zero-pad) from TP rows -> floor in regs ----
    float fl[8];
    #pragma unroll
    for (int to = 0; to < 8; ++to) {
        float acc = 0.0f;
        #pragma unroll
        for (int df = -2; df <= 2; ++df) {
            const int ff = f + df;
            if (ff >= 0 && ff < NF) acc += TPl[to * GSTR + ff];
        }
        fl[to] = fmaxf(acc * (1.0f / 5.0f), 1e-6f);
    }
    float fl256 = 0.0f;
    if (tid < 8) {
        fl256 = fmaxf((TPl[tid * GSTR + 254] + TPl[tid * GSTR + 255] +
                       TPl[tid * GSTR + 256]) * (1.0f / 5.0f), 1e-6f);
    }
    // NO barrier: phase D writes gr/gi, disjoint from TP region.

    // ---- phase D: mask -> staging rows gr/gi ----
    {
        #pragma unroll
        for (int ft = 0; ft < 8; ++ft) {
            const int t = t0 + ft;
            float grv = 0.0f, giv = 0.0f;
            if (t < NT) {
                const float flv = fl[ft];
                const float2 e2 = unpack_bf2(g[(b * NT + t) * NF + f]);
                const float a = sqrtf_fast(e2.x * e2.x + e2.y * e2.y);
                const float emag = fmaxf(a, 1e-6f);
                const float xarg = (emag - 1.5f * flv) * rcpf(0.15f * flv + 1e-6f);
                const float mask = rcpf(1.0f + __expf(-xarg));
                const float fm = 0.08f + 0.92f * (0.65f + 0.35f * mask);
                const float scale = emag * fm * rcpf(fmaxf(a, 1e-12f));
                grv = e2.x * scale; giv = e2.y * scale;
            }
            gr[ft * GSTR + f] = grv;
            gi[ft * GSTR + f] = giv;
        }
    }
    if (tid < 8) {   // f = 256 column of each frame
        const int ft = tid;
        const int t = t0 + ft;
        float grv = 0.0f, giv = 0.0f;
        if (t < NT) {
            const float flv = fl256;
            const float2 e2 = unpack_bf2(g[(b * NT + t) * NF + 256]);
            const float a = sqrtf_fast(e2.x * e2.x + e2.y * e2.y);
            const float emag = fmaxf(a, 1e-6f);
            const float xarg = (emag - 1.5f * flv) * rcpf(0.15f * flv + 1e-6f);
            const float mask = rcpf(1.0f + __expf(-xarg));
            const float fm = 0.08f + 0.92f * (0.65f + 0.35f * mask);
            const float scale = emag * fm * rcpf(fmaxf(a, 1e-12f));
            grv = e2.x * scale; giv = e2.y * scale;
        }
        gr[ft * GSTR + 256] = grv;
        gi[ft * GSTR + 256] = giv;
    }
    __syncthreads();   // staging rows written by all threads; FFT reads cross-wave

    // ---- inverse FFT: wave w handles frames ta = t0+2w, t0+2w+1 packed ----
    float* g0r = gr + (2*w) * GSTR;      float* g0i = gi + (2*w) * GSTR;
    float* g1r = gr + (2*w + 1) * GSTR;  float* g1i = gi + (2*w + 1) * GSTR;
    float* ar = g0r;   // FFT region = this wave's two staging rows (528 floats)
    float* ai = g0i;

    // pass 0: build packed C(n) = G1full + i*G2full from staging, dft8,
    // write back into the same region (all reads precede all writes).
    {
        float vr[8], vi[8];
        #pragma unroll
        for (int r = 0; r < 8; ++r) {
            const int n = j + 64*r;
            float cr, ci;
            if (n <= 256) {
                cr = g0r[n] - g1i[n];
                ci = g0i[n] + g1r[n];
            } else {
                const int m = 512 - n;
                cr = g0r[m] + g1i[m];
                ci = g1r[m] - g0i[m];
            }
            vr[r] = cr; vi[r] = ci;
        }
        dft8(vr, vi, 1.0f);
        #pragma unroll
        for (int r = 0; r < 8; ++r) { ar[P(8*j + r)] = vr[r]; ai[P(8*j + r)] = vi[r]; }
    }
    fft_pass<8>(ar, ai, j, 1.0f);
    float xr[8], xi[8];
    fft_pass_last(ar, ai, j, 1.0f, xr, xi);

    // window in place: Re plane = frame ta, Im plane = frame ta+1
    {
        float wdv[8];
        hann8(j, wdv);
        #pragma unroll
        for (int r = 0; r < 8; ++r) {
            const int n = j + 64*r;
            const float wd = wdv[r] * (1.0f / 512.0f);
            ar[P(n)] = xr[r] * wd;
            ai[P(n)] = xi[r] * wd;
        }
    }
    __syncthreads();

    // OLA: samples i in [t0*128, t0*128 + 1408) (padded coords)
    const int i0 = t0 << 7;
    if (t0 >= 3 && t0 + 10 <= NT - 1) {
        // interior fast path (155/157 blocks): every sample covered by exactly
        // 4 frames globally -> winv = 2/3 const; jj always in range.
        for (int s = tid; s < 1408; s += 256) {
            const int i = i0 + s;
            const int tl = (i - 384) >> 7;
            const int th = tl + 3;
            const int ca = tl > t0 ? tl : t0;
            const int cb = th < t0 + 7 ? th : t0 + 7;
            float acc = 0.0f;
            for (int t = ca; t <= cb; ++t) {
                const int ft = t - t0;
                const int n = i - (t << 7);
                acc += ((ft & 1) ? gi : gr)[(ft >> 1) * FBUF + P(n)];
            }
            const float v = acc * (2.0f / 3.0f);
            const int jj = i - PADC;
            if (tl >= t0 && th <= t0 + 7) out[b * LEN + jj] = v;    // unique owner
            else atomicAdd(out + b * LEN + jj, v);                  // boundary partial
        }
    } else {
        for (int s = tid; s < 1408; s += 256) {
            const int i = i0 + s;
            const int jj = i - PADC;
            if (jj < 0 || jj >= LEN) continue;
            const int tl = (i >= 384) ? ((i - 384) >> 7) : 0;
            int th = i >> 7; if (th > NT - 1) th = NT - 1;
            const int ca = tl > t0 ? tl : t0;
            const int cb = th < t0 + 7 ? th : t0 + 7;
            if (cb < ca) continue;
            float acc = 0.0f;
            for (int t = ca; t <= cb; ++t) {
                const int ft = t - t0;
                const int n = i - (t << 7);
                acc += ((ft & 1) ? gi : gr)[(ft >> 1) * FBUF + P(n)];
            }
            float winv;
            if (th - tl == 3) winv = (2.0f / 3.0f);   // COLA: sum hann^2 = 1.5
            else {
                float wacc = 0.0f;
                for (int t = tl; t <= th; ++t) {
                    const float wd = hann(i - (t << 7));
                    wacc += wd * wd;
                }
                winv = rcpf(fmaxf(wacc, 1e-11f));
            }
            const float v = acc * winv;
            if (tl >= t0 && th <= t0 + 7) out[b * LEN + jj] = v;
            else atomicAdd(out + b * LEN + jj, v);
        }
    }
}

extern "C" void kernel_launch(void* const* d_in, const int* in_sizes, int n_in,
                              void* d_out, int out_size, void* d_ws, size_t ws_size,
                              hipStream_t stream) {
    const float* noisy    = (const float*)d_in[0];
    const float* enhanced = (const float*)d_in[1];
    float* out = (float*)d_out;

    // workspace layout (float offsets), total ~31 MB:
    //   e_spec : [0, 5144112)               (16*1251*257 bf16x2 = 4B each)
    //   n_mag  : [5144112, 6430140)         (bf16, 2B each)
    float* ws = (float*)d_ws;
    __hip_bfloat162* e_spec = (__hip_bfloat162*)ws;
    __hip_bfloat16* n_mag = (__hip_bfloat16*)(ws + 5144112);

    stft_kernel<<<dim3((NT + 3) / 4, BATCH), dim3(256), 0, stream>>>(enhanced, noisy, e_spec, n_mag, out);
    floor_mask_istft_kernel<<<dim3((NT + 7) / 8, BATCH), dim3(256), 0, stream>>>(e_spec, n_mag, out);
}

// Round 8
// 120.559 us; speedup vs baseline: 1.0220x; 1.0220x over previous
//
#include <hip/hip_runtime.h>
#include <hip/hip_bf16.h>
#include <math.h>

#define BATCH 16
#define LEN   160000
#define NFFT  512
#define HOP   128
#define NT    1251      // 1 + (160000+512-512)/128
#define NF    257
#define PADC  256
#define TWO_PI 6.28318530717958647692f
// padded LDS index: +1 float per 32 -> breaks power-of-2 bank aliasing
#define P(i) ((i) + ((i) >> 5))
#define FBUF 528        // padded 512-float FFT region (P(511)=526 < 528)
#define GSTR 264        // staging row stride: 2 rows == FBUF exactly

typedef unsigned int u32;
typedef unsigned short u16t;

__device__ __forceinline__ float rcpf(float x)  { return __builtin_amdgcn_rcpf(x); }
__device__ __forceinline__ float sqrtf_fast(float x) { return __builtin_amdgcn_sqrtf(x); }

__device__ __forceinline__ int reflect_idx(int j) {
    j = j < 0 ? -j : j;
    j = j >= LEN ? 2*LEN - 2 - j : j;
    return j;
}

__device__ __forceinline__ float hann(int n) {
    return 0.5f - 0.5f * __cosf(TWO_PI * (float)n * (1.0f / 512.0f));
}

// hann(j + 64r) for r=0..7 from ONE sincos: cos(th + r*pi/4) expanded over
// compile-time constants.
__device__ __forceinline__ void hann8(int j, float wdv[8]) {
    float sth, cth;
    __sincosf((TWO_PI / 512.0f) * (float)j, &sth, &cth);
    const float K8 = 0.70710678118654752f;
    const float A = 0.5f * K8 * (cth - sth);
    const float B = 0.5f * K8 * (cth + sth);
    wdv[0] = 0.5f - 0.5f * cth;
    wdv[1] = 0.5f - A;
    wdv[2] = 0.5f + 0.5f * sth;
    wdv[3] = 0.5f + B;
    wdv[4] = 0.5f + 0.5f * cth;
    wdv[5] = 0.5f + A;
    wdv[6] = 0.5f - 0.5f * sth;
    wdv[7] = 0.5f - B;
}

__device__ __forceinline__ __hip_bfloat162 pack_bf2(float x, float y) {
    __hip_bfloat162 r; r.x = __float2bfloat16(x); r.y = __float2bfloat16(y); return r;
}
__device__ __forceinline__ float2 unpack_bf2(__hip_bfloat162 v) {
    return make_float2(__bfloat162float(v.x), __bfloat162float(v.y));
}

// ---------- scalar sorted-4-smallest (used only for the f=256 column) ----------
struct T4 { float m0, m1, m2, m3; };   // ascending

__device__ __forceinline__ void ins(T4& a, float v) {
    const float x0 = fminf(a.m0, v);  const float c0 = fmaxf(a.m0, v);
    const float x1 = fminf(a.m1, c0); const float c1 = fmaxf(a.m1, c0);
    const float x2 = fminf(a.m2, c1); const float c2 = fmaxf(a.m2, c1);
    const float x3 = fminf(a.m3, c2);
    a.m0 = x0; a.m1 = x1; a.m2 = x2; a.m3 = x3;
}

// ---------- PACKED u16 sorted-4-smallest via FORCED v_pk_min/max_u16 ----------
// n_mag is strictly positive bf16 -> u16 bit order == value order.
__device__ __forceinline__ u32 pminP(u32 a, u32 b) {
    u32 d; asm("v_pk_min_u16 %0, %1, %2" : "=v"(d) : "v"(a), "v"(b)); return d;
}
__device__ __forceinline__ u32 pmaxP(u32 a, u32 b) {
    u32 d; asm("v_pk_max_u16 %0, %1, %2" : "=v"(d) : "v"(a), "v"(b)); return d;
}

struct PT4 { u32 m0, m1, m2, m3; };   // ascending per 16-bit lane

__device__ __forceinline__ void insP(PT4& a, u32 v) {
    const u32 x0 = pminP(a.m0, v);  const u32 c0 = pmaxP(a.m0, v);
    const u32 x1 = pminP(a.m1, c0); const u32 c1 = pmaxP(a.m1, c0);
    const u32 x2 = pminP(a.m2, c1); const u32 c2 = pmaxP(a.m2, c1);
    const u32 x3 = pminP(a.m3, c2);
    a.m0 = x0; a.m1 = x1; a.m2 = x2; a.m3 = x3;
}

__device__ __forceinline__ PT4 sort4P(u32 a, u32 b, u32 c, u32 d) {
    const u32 x0 = pminP(a, b), x1 = pmaxP(a, b);
    const u32 x2 = pminP(c, d), x3 = pmaxP(c, d);
    const u32 y0 = pminP(x0, x2), y2 = pmaxP(x0, x2);
    const u32 y1 = pminP(x1, x3), y3 = pmaxP(x1, x3);
    PT4 r; r.m0 = y0; r.m1 = pminP(y1, y2); r.m2 = pmaxP(y1, y2); r.m3 = y3;
    return r;
}

__device__ __forceinline__ u32 merge4_m3P(const PT4& a, const PT4& b) {
    const u32 l0 = pminP(a.m0, b.m3);
    const u32 l1 = pminP(a.m1, b.m2);
    const u32 l2 = pminP(a.m2, b.m1);
    const u32 l3 = pminP(a.m3, b.m0);
    return pmaxP(pmaxP(l0, l1), pmaxP(l2, l3));
}

// 8-point DFT in registers. y[m] = sum_r v[r] * exp(sign*2*pi*i*r*m/8).
__device__ __forceinline__ void dft8(float vr[8], float vi[8], float sign) {
    const float K = 0.70710678118654752f;
    float ar=vr[0]+vr[4], ai=vi[0]+vi[4];
    float br=vr[0]-vr[4], bi=vi[0]-vi[4];
    float cr=vr[2]+vr[6], ci=vi[2]+vi[6];
    float dr=vr[2]-vr[6], di=vi[2]-vi[6];
    float er=vr[1]+vr[5], ei=vi[1]+vi[5];
    float fr=vr[1]-vr[5], fi=vi[1]-vi[5];
    float gr=vr[3]+vr[7], gi=vi[3]+vi[7];
    float hr=vr[3]-vr[7], hi=vi[3]-vi[7];
    const float W4dr = -sign*di, W4di = sign*dr;
    const float W4hr = -sign*hi, W4hi = sign*hr;
    const float E0r=ar+cr, E0i=ai+ci, E2r=ar-cr, E2i=ai-ci;
    const float E1r=br+W4dr, E1i=bi+W4di, E3r=br-W4dr, E3i=bi-W4di;
    const float O0r=er+gr, O0i=ei+gi, O2r=er-gr, O2i=ei-gi;
    const float O1r=fr+W4hr, O1i=fi+W4hi, O3r=fr-W4hr, O3i=fi-W4hi;
    const float T1r = K*(O1r - sign*O1i), T1i = K*(O1i + sign*O1r);
    const float T2r = -sign*O2i,          T2i = sign*O2r;
    const float T3r = K*(-O3r - sign*O3i), T3i = K*(-O3i + sign*O3r);
    vr[0]=E0r+O0r; vi[0]=E0i+O0i;  vr[4]=E0r-O0r; vi[4]=E0i-O0i;
    vr[1]=E1r+T1r; vi[1]=E1i+T1i;  vr[5]=E1r-T1r; vi[5]=E1i-T1i;
    vr[2]=E2r+T2r; vi[2]=E2i+T2i;  vr[6]=E2r-T2r; vi[6]=E2i-T2i;
    vr[3]=E3r+T3r; vi[3]=E3i+T3i;  vr[7]=E3r-T3r; vi[7]=E3i-T3i;
}

// One Stockham radix-8 pass, IN PLACE, one wave = one FFT (j in 0..63).
template<int NS>
__device__ __forceinline__ void fft_pass(float* R, float* I, int j, float sign) {
    float vr[8], vi[8];
    #pragma unroll
    for (int r = 0; r < 8; ++r) { vr[r] = R[P(j + 64*r)]; vi[r] = I[P(j + 64*r)]; }
    const float th = sign * (TWO_PI / (8.0f * (float)NS)) * (float)(j & (NS - 1));
    float w1r, w1i; __sincosf(th, &w1i, &w1r);
    float wr = w1r, wi = w1i;
    #pragma unroll
    for (int r = 1; r < 8; ++r) {
        const float tr = vr[r]*wr - vi[r]*wi;
        vi[r] = vr[r]*wi + vi[r]*wr; vr[r] = tr;
        const float nwr = wr*w1r - wi*w1i;
        wi = wr*w1i + wi*w1r; wr = nwr;
    }
    dft8(vr, vi, sign);
    const int base = ((j / NS) * (8 * NS)) + (j & (NS - 1));
    #pragma unroll
    for (int r = 0; r < 8; ++r) { R[P(base + r*NS)] = vr[r]; I[P(base + r*NS)] = vi[r]; }
}

// Final pass (NS=64): results stay in REGISTERS.
__device__ __forceinline__ void fft_pass_last(const float* R, const float* I, int j,
                                              float sign, float vr[8], float vi[8]) {
    #pragma unroll
    for (int r = 0; r < 8; ++r) { vr[r] = R[P(j + 64*r)]; vi[r] = I[P(j + 64*r)]; }
    const float th = sign * (TWO_PI / 512.0f) * (float)j;
    float w1r, w1i; __sincosf(th, &w1i, &w1r);
    float wr = w1r, wi = w1i;
    #pragma unroll
    for (int r = 1; r < 8; ++r) {
        const float tr = vr[r]*wr - vi[r]*wi;
        vi[r] = vr[r]*wi + vi[r]*wr; vr[r] = tr;
        const float nwr = wr*w1r - wi*w1i;
        wi = wr*w1i + wi*w1r; wr = nwr;
    }
    dft8(vr, vi, sign);
}

// K1: STFT of BOTH signals via one complex FFT per frame: z = enh + i*noi.
// Unchanged (also zeroes the OLA output buffer).
__global__ __launch_bounds__(256, 6) void stft_kernel(const float* __restrict__ enh,
                                                      const float* __restrict__ noi,
                                                      __hip_bfloat162* __restrict__ e_spec,
                                                      __hip_bfloat16*  __restrict__ n_mag,
                                                      float* __restrict__ out) {
    __shared__ float Ar[4*FBUF], Ai[4*FBUF];
    const int tid = threadIdx.x;
    const int w = tid >> 6, j = tid & 63;
    const int tr_ = blockIdx.x * 4 + w;
    const bool live = tr_ < NT;
    const int t = live ? tr_ : NT - 1;
    const int b = blockIdx.y;
    float* ar = Ar + w*FBUF; float* ai = Ai + w*FBUF;

    // zero the output slice (fire-and-forget stores; K3 waits on this kernel)
    {
        const int z = (blockIdx.x << 9) + (tid << 1);
        if (z < LEN) *reinterpret_cast<float2*>(out + (size_t)b * LEN + z) = make_float2(0.0f, 0.0f);
    }

    // pass 0: global -> registers (windowed), dft8, write A
    {
        const int sbase = t * HOP - PADC;
        float vr[8], vi[8];
        if (sbase >= 0 && sbase + NFFT <= LEN) {
            const float* __restrict__ pe = enh + b * LEN + sbase;
            const float* __restrict__ pn = noi + b * LEN + sbase;
            float wdv[8];
            hann8(j, wdv);
            #pragma unroll
            for (int r = 0; r < 8; ++r) {
                const int n = j + 64*r;
                vr[r] = pe[n] * wdv[r];
                vi[r] = pn[n] * wdv[r];
            }
        } else {
            const float* __restrict__ pe = enh + b * LEN;
            const float* __restrict__ pn = noi + b * LEN;
            #pragma unroll
            for (int r = 0; r < 8; ++r) {
                const int n = j + 64*r;
                const int idx = reflect_idx(sbase + n);
                const float wd = hann(n);
                vr[r] = pe[idx] * wd;
                vi[r] = pn[idx] * wd;
            }
        }
        dft8(vr, vi, -1.0f);
        #pragma unroll
        for (int r = 0; r < 8; ++r) { ar[P(8*j + r)] = vr[r]; ai[P(8*j + r)] = vi[r]; }
    }
    fft_pass<8>(ar, ai, j, -1.0f);
    float zr[8], zi[8];
    fft_pass_last(ar, ai, j, -1.0f, zr, zi);

    // Hermitian partner via cross-lane shuffle (regs 4..7 of lane (64-j)&63)
    const int src = (64 - j) & 63;
    float pr[4], pi_[4];
    #pragma unroll
    for (int q = 4; q < 8; ++q) {
        pr[q-4]  = __shfl(zr[q], src);
        pi_[q-4] = __shfl(zi[q], src);
    }
    if (live) {
        const int obase = (b * NT + t) * NF;
        #pragma unroll
        for (int r = 0; r < 4; ++r) {
            const int kk = j + 64*r;
            const float yr = (j == 0) ? zr[(8 - r) & 7] : pr[3 - r];
            const float yi = (j == 0) ? zi[(8 - r) & 7] : pi_[3 - r];
            const float er = 0.5f*(zr[r] + yr), ei = 0.5f*(zi[r] - yi);
            const float nr = 0.5f*(zi[r] + yi), ni = 0.5f*(yr - zr[r]);
            e_spec[obase + kk] = pack_bf2(er, ei);
            n_mag[obase + kk] = __float2bfloat16(fmaxf(sqrtf_fast(nr*nr + ni*ni), 1e-6f));
        }
        if (j == 0) {   // kk = 256: self-conjugate bin
            e_spec[obase + 256] = pack_bf2(zr[4], 0.0f);
            n_mag[obase + 256] = __float2bfloat16(fmaxf(fabsf(zi[4]), 1e-6f));
        }
    }
}

// Packed two-stacks quantile, 12 windows per call (group offset 6): windows
// i=0..5 in lo16, i=6..11 in hi16. Rows r relative to `base`.
// Suffix S[i] over W[i..6); single prefix chain streamed over W[6..36).
// Exact 4th-smallest (order-independent network) -> bit-identical floor.
template<bool CL>
__device__ __forceinline__ void phaseQ12(const u16t* __restrict__ pbu,
                                         int base, int f, float qv[12]) {
    u16t w0[12];
    #pragma unroll
    for (int r = 0; r < 12; ++r) {
        int tr = base + r;
        if (CL) { tr = tr < 0 ? 0 : (tr > NT - 1 ? NT - 1 : tr); }
        w0[r] = pbu[tr * NF + f];
    }
    PT4 S[6];
    S[5].m0 = (u32)w0[5] | ((u32)w0[11] << 16);
    S[5].m1 = S[5].m2 = S[5].m3 = 0xFFFFFFFFu;
    #pragma unroll
    for (int k = 4; k >= 0; --k) {
        S[k] = S[k+1];
        insP(S[k], (u32)w0[k] | ((u32)w0[k+6] << 16));
    }
    // ring[r%6] holds w[r] (lo element) for the prefix stream; W[r]={w[r],w[r+6]}
    u16t ring[6];
    #pragma unroll
    for (int i = 0; i < 6; ++i) ring[i] = w0[6 + i];
    PT4 Pp;
    {
        u32 Wt[4];
        #pragma unroll
        for (int r = 6; r < 10; ++r) {
            int tr = base + r + 6;
            if (CL) { tr = tr < 0 ? 0 : (tr > NT - 1 ? NT - 1 : tr); }
            const u16t hi = pbu[tr * NF + f];
            Wt[r - 6] = (u32)ring[r % 6] | ((u32)hi << 16);
            ring[r % 6] = hi;
        }
        Pp = sort4P(Wt[0], Wt[1], Wt[2], Wt[3]);
    }
    #pragma unroll
    for (int r = 10; r < 31; ++r) {
        int tr = base + r + 6;
        if (CL) { tr = tr < 0 ? 0 : (tr > NT - 1 ? NT - 1 : tr); }
        const u16t hi = pbu[tr * NF + f];
        insP(Pp, (u32)ring[r % 6] | ((u32)hi << 16));
        ring[r % 6] = hi;
    }
    {
        const u32 m = merge4_m3P(S[0], Pp);
        qv[0] = __uint_as_float(m << 16);
        qv[6] = __uint_as_float(m & 0xFFFF0000u);
    }
    #pragma unroll
    for (int k = 1; k < 6; ++k) {
        const int r = 30 + k;
        int tr = base + r + 6;
        if (CL) { tr = tr < 0 ? 0 : (tr > NT - 1 ? NT - 1 : tr); }
        const u16t hi = pbu[tr * NF + f];
        insP(Pp, (u32)ring[r % 6] | ((u32)hi << 16));
        ring[r % 6] = hi;
        const u32 m = merge4_m3P(S[k], Pp);
        qv[k]     = __uint_as_float(m << 16);
        qv[6 + k] = __uint_as_float(m & 0xFFFF0000u);
    }
}

// K3 (FUSED, 16-frame tile, 512 threads / 8 waves). Frames t0..t0+15 span
// padded samples [t0*128, t0*128 + 15*128 + 512) -> OLA walks 2432 samples
// (R7 bug: walked 2304, dropping frame t0+15's n in [384,512) tail).
__global__ __launch_bounds__(512, 6) void floor_mask_istft_kernel(
        const __hip_bfloat162* __restrict__ g,
        const __hip_bfloat16* __restrict__ n_mag,
        float* __restrict__ out) {
    __shared__ float smem[40 * GSTR];
    float (*q)[GSTR] = reinterpret_cast<float (*)[GSTR]>(smem);  // rows 0..23
    float* TPl = smem + 24 * GSTR;      // 16 time-pooled rows (24..39)
    float* gr = smem;                   // staging frames 0..15 (aliases q)
    float* gi = smem + 16 * GSTR;       // staging frames 0..15 (aliases q/TP)

    const int tid = threadIdx.x;
    const int w = tid >> 6, j = tid & 63;   // 8 waves
    const int h = tid >> 8, f = tid & 255;  // half index / freq bin
    const int t0 = blockIdx.x * 16, b = blockIdx.y;
    const __hip_bfloat16* __restrict__ pb = n_mag + b * NT * NF;
    const u16t* __restrict__ pbu = (const u16t*)pb;

    // ---- phase Q: half h computes quantile windows k = 12h..12h+11 ----
    {
        float qv[12];
        const int base = t0 - 19 + 12 * h;
        if (t0 >= 19 && t0 + 34 <= NT - 1) {       // interior: no clamp
            phaseQ12<false>(pbu, base, f, qv);
        } else {
            phaseQ12<true>(pbu, base, f, qv);
            #pragma unroll
            for (int i = 0; i < 12; ++i) {         // zero-pad rows outside [0,NT)
                const int tq = t0 - 4 + 12 * h + i;
                if (tq < 0 || tq >= NT) qv[i] = 0.0f;
            }
        }
        #pragma unroll
        for (int i = 0; i < 12; ++i) q[12 * h + i][f] = qv[i];
    }
    // f = 256 column: threads 0..23 (wave 0), one scalar window each
    if (tid < 24) {
        const int k = tid;
        T4 m; m.m0 = m.m1 = m.m2 = m.m3 = 3.4e38f;
        for (int dt = -15; dt <= 15; ++dt) {
            int tt = t0 - 4 + k + dt;
            tt = tt < 0 ? 0 : (tt > NT - 1 ? NT - 1 : tt);
            ins(m, __bfloat162float(pb[tt * NF + 256]));
        }
        float qk = m.m3;
        const int tq = t0 - 4 + k;
        if (tq < 0 || tq >= NT) qk = 0.0f;
        q[k][256] = qk;
    }
    __syncthreads();   // bar1: q[24] rows complete

    // ---- time pool k=9: thread (h,f) produces TP rows 8h..8h+7 ----
    {
        float qr[16];
        #pragma unroll
        for (int i = 0; i < 16; ++i) qr[i] = q[8 * h + i][f];
        float acc = 0.0f;
        #pragma unroll
        for (int i = 0; i < 9; ++i) acc += qr[i];
        #pragma unroll
        for (int ft_ = 0; ft_ < 8; ++ft_) {
            TPl[(8 * h + ft_) * GSTR + f] = acc * (1.0f / 9.0f);
            if (ft_ < 7) acc += qr[ft_ + 9] - qr[ft_];
        }
    }
    if (tid < 16) {   // f = 256 TP rows
        float acc = 0.0f;
        #pragma unroll
        for (int d = 0; d < 9; ++d) acc += q[tid + d][256];
        TPl[tid * GSTR + 256] = acc * (1.0f / 9.0f);
    }
    __syncthreads();   // bar2: TP rows complete

    // ---- freq pool k=5 (zero-pad) -> floor in regs for frames 8h..8h+7 ----
    float fl[8];
    #pragma unroll
    for (int ft_ = 0; ft_ < 8; ++ft_) {
        const int row = 8 * h + ft_;
        float acc = 0.0f;
        #pragma unroll
        for (int df = -2; df <= 2; ++df) {
            const int ff = f + df;
            if (ff >= 0 && ff < NF) acc += TPl[row * GSTR + ff];
        }
        fl[ft_] = fmaxf(acc * (1.0f / 5.0f), 1e-6f);
    }
    float fl256 = 0.0f;
    if (tid < 16) {
        fl256 = fmaxf((TPl[tid * GSTR + 254] + TPl[tid * GSTR + 255] +
                       TPl[tid * GSTR + 256]) * (1.0f / 5.0f), 1e-6f);
    }
    __syncthreads();   // bar3: all pool reads done before staging overwrites q/TP

    // ---- phase D: mask -> staging rows gr/gi ----
    {
        #pragma unroll
        for (int ft_ = 0; ft_ < 8; ++ft_) {
            const int ft = 8 * h + ft_;
            const int t = t0 + ft;
            float grv = 0.0f, giv = 0.0f;
            if (t < NT) {
                const float flv = fl[ft_];
                const float2 e2 = unpack_bf2(g[(b * NT + t) * NF + f]);
                const float a = sqrtf_fast(e2.x * e2.x + e2.y * e2.y);
                const float emag = fmaxf(a, 1e-6f);
                const float xarg = (emag - 1.5f * flv) * rcpf(0.15f * flv + 1e-6f);
                const float mask = rcpf(1.0f + __expf(-xarg));
                const float fm = 0.08f + 0.92f * (0.65f + 0.35f * mask);
                const float scale = emag * fm * rcpf(fmaxf(a, 1e-12f));
                grv = e2.x * scale; giv = e2.y * scale;
            }
            gr[ft * GSTR + f] = grv;
            gi[ft * GSTR + f] = giv;
        }
    }
    if (tid < 16) {   // f = 256 column of each frame
        const int ft = tid;
        const int t = t0 + ft;
        float grv = 0.0f, giv = 0.0f;
        if (t < NT) {
            const float2 e2 = unpack_bf2(g[(b * NT + t) * NF + 256]);
            const float a = sqrtf_fast(e2.x * e2.x + e2.y * e2.y);
            const float emag = fmaxf(a, 1e-6f);
            const float xarg = (emag - 1.5f * fl256) * rcpf(0.15f * fl256 + 1e-6f);
            const float mask = rcpf(1.0f + __expf(-xarg));
            const float fm = 0.08f + 0.92f * (0.65f + 0.35f * mask);
            const float scale = emag * fm * rcpf(fmaxf(a, 1e-12f));
            grv = e2.x * scale; giv = e2.y * scale;
        }
        gr[ft * GSTR + 256] = grv;
        gi[ft * GSTR + 256] = giv;
    }
    __syncthreads();   // bar4: staging complete; FFT reads cross-thread rows

    // ---- inverse FFT: wave w handles frames 2w, 2w+1 packed ----
    float* g0r = gr + (2*w) * GSTR;      float* g0i = gi + (2*w) * GSTR;
    float* g1r = gr + (2*w + 1) * GSTR;  float* g1i = gi + (2*w + 1) * GSTR;
    float* ar = g0r;   // FFT region = this wave's two staging rows (528 floats)
    float* ai = g0i;

    {
        float vr[8], vi[8];
        #pragma unroll
        for (int r = 0; r < 8; ++r) {
            const int n = j + 64*r;
            float cr, ci;
            if (n <= 256) {
                cr = g0r[n] - g1i[n];
                ci = g0i[n] + g1r[n];
            } else {
                const int m = 512 - n;
                cr = g0r[m] + g1i[m];
                ci = g1r[m] - g0i[m];
            }
            vr[r] = cr; vi[r] = ci;
        }
        dft8(vr, vi, 1.0f);
        #pragma unroll
        for (int r = 0; r < 8; ++r) { ar[P(8*j + r)] = vr[r]; ai[P(8*j + r)] = vi[r]; }
    }
    fft_pass<8>(ar, ai, j, 1.0f);
    float xr[8], xi[8];
    fft_pass_last(ar, ai, j, 1.0f, xr, xi);

    // window in place: Re plane = frame 2w, Im plane = frame 2w+1
    {
        float wdv[8];
        hann8(j, wdv);
        #pragma unroll
        for (int r = 0; r < 8; ++r) {
            const int n = j + 64*r;
            const float wd = wdv[r] * (1.0f / 512.0f);
            ar[P(n)] = xr[r] * wd;
            ai[P(n)] = xi[r] * wd;
        }
    }
    __syncthreads();   // bar5

    // OLA: samples i in [t0*128, t0*128 + 2432) (padded coords; 15*128+512)
    const int i0 = t0 << 7;
    if (t0 >= 3 && t0 + 18 <= NT - 1) {
        // interior fast path: every sample covered by exactly 4 frames
        // globally -> winv = 2/3 const; jj always in range.
        for (int s = tid; s < 2432; s += 512) {
            const int i = i0 + s;
            const int tl = (i - 384) >> 7;
            const int th = tl + 3;
            const int ca = tl > t0 ? tl : t0;
            const int cb = th < t0 + 15 ? th : t0 + 15;
            float acc = 0.0f;
            for (int t = ca; t <= cb; ++t) {
                const int ft = t - t0;
                const int n = i - (t << 7);
                acc += ((ft & 1) ? gi : gr)[(ft >> 1) * FBUF + P(n)];
            }
            const float v = acc * (2.0f / 3.0f);
            const int jj = i - PADC;
            if (tl >= t0 && th <= t0 + 15) out[b * LEN + jj] = v;   // unique owner
            else atomicAdd(out + b * LEN + jj, v);                  // boundary partial
        }
    } else {
        for (int s = tid; s < 2432; s += 512) {
            const int i = i0 + s;
            const int jj = i - PADC;
            if (jj < 0 || jj >= LEN) continue;
            const int tl = (i >= 384) ? ((i - 384) >> 7) : 0;
            int th = i >> 7; if (th > NT - 1) th = NT - 1;
            const int ca = tl > t0 ? tl : t0;
            const int cb = th < t0 + 15 ? th : t0 + 15;
            if (cb < ca) continue;
            float acc = 0.0f;
            for (int t = ca; t <= cb; ++t) {
                const int ft = t - t0;
                const int n = i - (t << 7);
                acc += ((ft & 1) ? gi : gr)[(ft >> 1) * FBUF + P(n)];
            }
            float winv;
            if (th - tl == 3) winv = (2.0f / 3.0f);   // COLA: sum hann^2 = 1.5
            else {
                float wacc = 0.0f;
                for (int t = tl; t <= th; ++t) {
                    const float wd = hann(i - (t << 7));
                    wacc += wd * wd;
                }
                winv = rcpf(fmaxf(wacc, 1e-11f));
            }
            const float v = acc * winv;
            if (tl >= t0 && th <= t0 + 15) out[b * LEN + jj] = v;
            else atomicAdd(out + b * LEN + jj, v);
        }
    }
}

extern "C" void kernel_launch(void* const* d_in, const int* in_sizes, int n_in,
                              void* d_out, int out_size, void* d_ws, size_t ws_size,
                              hipStream_t stream) {
    const float* noisy    = (const float*)d_in[0];
    const float* enhanced = (const float*)d_in[1];
    float* out = (float*)d_out;

    // workspace layout (float offsets), total ~31 MB:
    //   e_spec : [0, 5144112)               (16*1251*257 bf16x2 = 4B each)
    //   n_mag  : [5144112, 6430140)         (bf16, 2B each)
    float* ws = (float*)d_ws;
    __hip_bfloat162* e_spec = (__hip_bfloat162*)ws;
    __hip_bfloat16* n_mag = (__hip_bfloat16*)(ws + 5144112);

    stft_kernel<<<dim3((NT + 3) / 4, BATCH), dim3(256), 0, stream>>>(enhanced, noisy, e_spec, n_mag, out);
    floor_mask_istft_kernel<<<dim3((NT + 15) / 16, BATCH), dim3(512), 0, stream>>>(e_spec, n_mag, out);
}